// Round 4
// baseline (369.724 us; speedup 1.0000x reference)
//
#include <hip/hip_runtime.h>
#include <math.h>

#define BIGV 10000.0f

constexpr int B = 32, S = 4096, D = 512;
constexpr int C    = 32;          // blocks per batch
constexpr int L    = S / C;       // 128 rows per block
constexpr int WPB  = 4;           // waves per block (256 threads)
constexpr int RW   = L / WPB;     // 32 rows per wave
constexpr int NREC = B * C;       // 1024 block records
constexpr int RPB  = C;           // 32 records per batch

// ------------- kernel 1: barrier-free streaming + one LDS block-merge ------
__global__ __launch_bounds__(256, 4)
void pool_stream(const float* __restrict__ x, const int* __restrict__ mask,
                 const float* __restrict__ wvec, float* __restrict__ ws) {
  __shared__ float ls_o[WPB][D];
  __shared__ float ls_sm[WPB][D];
  __shared__ float ls_mx[WPB][D];
  __shared__ float ls_mn[WPB][D];
  __shared__ float ls_m[WPB], ls_l[WPB], ls_c[WPB];

  const int tid = threadIdx.x, lane = tid & 63, w = tid >> 6;
  const int blk = blockIdx.x, b = blk / C, c = blk % C;
  const int s0 = c * L + w * RW;

  const float4* row4 = (const float4*)(x + ((size_t)b * S + s0) * D);
  const int*    mr   = mask + (size_t)b * S + s0;

  const float4* wv4 = (const float4*)wvec;
  const float4  w0 = wv4[lane], w1 = wv4[64 + lane];

  float m = -INFINITY, l = 0.f, cnt = 0.f;
  float o[8], sm[8], mx[8], mn[8];
  #pragma unroll
  for (int j = 0; j < 8; ++j) { o[j] = 0.f; sm[j] = 0.f; mx[j] = -BIGV; mn[j] = BIGV; }

  // 4-row register pipeline, processed 2 rows per iteration
  float4 p0a = row4[lane],       p0b = row4[64 + lane];
  float4 p1a = row4[128 + lane], p1b = row4[192 + lane];
  float4 p2a = row4[256 + lane], p2b = row4[320 + lane];
  float4 p3a = row4[384 + lane], p3b = row4[448 + lane];
  int m0 = mr[0], m1 = mr[1], m2 = mr[2], m3 = mr[3];

  for (int r = 0; r < RW; r += 2) {
    const float4 c0a = p0a, c0b = p0b, c1a = p1a, c1b = p1b;
    const int cm0 = m0, cm1 = m1;
    p0a = p2a; p0b = p2b; p1a = p3a; p1b = p3b; m0 = m2; m1 = m3;
    if (r + 5 < RW) {
      p2a = row4[(size_t)(r + 4) * (D / 4) + lane];
      p2b = row4[(size_t)(r + 4) * (D / 4) + 64 + lane];
      p3a = row4[(size_t)(r + 5) * (D / 4) + lane];
      p3b = row4[(size_t)(r + 5) * (D / 4) + 64 + lane];
      m2 = mr[r + 4]; m3 = mr[r + 5];
    }

    // two independent dot reductions; butterfly chains interleave
    float d0 = 0.f, d1 = 0.f;
    d0 = fmaf(c0a.x, w0.x, d0); d0 = fmaf(c0a.y, w0.y, d0);
    d0 = fmaf(c0a.z, w0.z, d0); d0 = fmaf(c0a.w, w0.w, d0);
    d0 = fmaf(c0b.x, w1.x, d0); d0 = fmaf(c0b.y, w1.y, d0);
    d0 = fmaf(c0b.z, w1.z, d0); d0 = fmaf(c0b.w, w1.w, d0);
    d1 = fmaf(c1a.x, w0.x, d1); d1 = fmaf(c1a.y, w0.y, d1);
    d1 = fmaf(c1a.z, w0.z, d1); d1 = fmaf(c1a.w, w0.w, d1);
    d1 = fmaf(c1b.x, w1.x, d1); d1 = fmaf(c1b.y, w1.y, d1);
    d1 = fmaf(c1b.z, w1.z, d1); d1 = fmaf(c1b.w, w1.w, d1);
    #pragma unroll
    for (int off = 32; off; off >>= 1) {
      d0 += __shfl_xor(d0, off, 64);
      d1 += __shfl_xor(d1, off, 64);
    }

    #pragma unroll
    for (int h = 0; h < 2; ++h) {
      const float dsc = h ? d1 : d0;
      const int   cm  = h ? cm1 : cm0;
      const float xa[8] = {
        h ? c1a.x : c0a.x, h ? c1a.y : c0a.y, h ? c1a.z : c0a.z, h ? c1a.w : c0a.w,
        h ? c1b.x : c0b.x, h ? c1b.y : c0b.y, h ? c1b.z : c0b.z, h ? c1b.w : c0b.w };

      const float s = cm ? dsc : -BIGV;
      if (s > m) {                         // wave-uniform
        const float alpha = __expf(m - s); // exp(-inf)=0 on first row
        l *= alpha;
        #pragma unroll
        for (int j = 0; j < 8; ++j) o[j] *= alpha;
        m = s;
      }
      const float p = __expf(s - m);       // masked after any real row: exactly 0
      l += p;
      if (cm) {                            // wave-uniform fast path
        cnt += 1.f;
        #pragma unroll
        for (int j = 0; j < 8; ++j) {
          o[j]  = fmaf(p, xa[j], o[j]);
          sm[j] += xa[j];
          mx[j] = fmaxf(mx[j], xa[j]);
          mn[j] = fminf(mn[j], xa[j]);
        }
      } else if (p > 0.f) {                // only while all-masked prefix (p==1)
        #pragma unroll
        for (int j = 0; j < 8; ++j) o[j] += xa[j];
      }
    }
  }

  // ---- intra-block merge: 4 wave records -> 1 block record ----
  ((float4*)ls_o[w])[lane]       = make_float4(o[0], o[1], o[2], o[3]);
  ((float4*)ls_o[w])[64 + lane]  = make_float4(o[4], o[5], o[6], o[7]);
  ((float4*)ls_sm[w])[lane]      = make_float4(sm[0], sm[1], sm[2], sm[3]);
  ((float4*)ls_sm[w])[64 + lane] = make_float4(sm[4], sm[5], sm[6], sm[7]);
  ((float4*)ls_mx[w])[lane]      = make_float4(mx[0], mx[1], mx[2], mx[3]);
  ((float4*)ls_mx[w])[64 + lane] = make_float4(mx[4], mx[5], mx[6], mx[7]);
  ((float4*)ls_mn[w])[lane]      = make_float4(mn[0], mn[1], mn[2], mn[3]);
  ((float4*)ls_mn[w])[64 + lane] = make_float4(mn[4], mn[5], mn[6], mn[7]);
  if (lane == 0) { ls_m[w] = m; ls_l[w] = l; ls_c[w] = cnt; }
  __syncthreads();

  float m_blk = fmaxf(fmaxf(ls_m[0], ls_m[1]), fmaxf(ls_m[2], ls_m[3]));
  float al[WPB];
  float l_f = 0.f, c_f = 0.f;
  #pragma unroll
  for (int k = 0; k < WPB; ++k) {
    al[k] = __expf(ls_m[k] - m_blk);
    l_f += ls_l[k] * al[k];
    c_f += ls_c[k];
  }
  #pragma unroll
  for (int h = 0; h < 2; ++h) {
    const int col = h * 256 + tid;
    float of = 0.f, sf = 0.f, xf = -BIGV, nf = BIGV;
    #pragma unroll
    for (int k = 0; k < WPB; ++k) {
      of = fmaf(ls_o[k][col], al[k], of);
      sf += ls_sm[k][col];
      xf  = fmaxf(xf, ls_mx[k][col]);
      nf  = fminf(nf, ls_mn[k][col]);
    }
    const size_t rec = (size_t)blk;
    ws[rec * D + col]                        = of;
    ws[(size_t)NREC * D + rec * D + col]     = sf;
    ws[2 * (size_t)NREC * D + rec * D + col] = xf;
    ws[3 * (size_t)NREC * D + rec * D + col] = nf;
  }
  if (tid == 0) {
    float* scal = ws + 4 * (size_t)NREC * D;
    scal[blk]            = m_blk;
    scal[NREC + blk]     = l_f;
    scal[2 * NREC + blk] = c_f;
  }
}

// ------------- kernel 2: flash-merge 32 records per batch ------------------
__global__ __launch_bounds__(128)
void pool_merge(const float* __restrict__ ws, float* __restrict__ out) {
  const int b = blockIdx.x, q = blockIdx.y, tid = threadIdx.x;
  const int col = q * 128 + tid;
  const float* scal = ws + 4 * (size_t)NREC * D;
  const int r0 = b * RPB;

  float m_f = -INFINITY;
  #pragma unroll 8
  for (int i = 0; i < RPB; ++i) m_f = fmaxf(m_f, scal[r0 + i]);

  float Lsum = 0.f, CNT = 0.f;
  float o = 0.f, sm = 0.f, mx = -BIGV, mn = BIGV;
  #pragma unroll 4
  for (int i = 0; i < RPB; ++i) {
    const size_t rec = (size_t)(r0 + i);
    const float a = __expf(scal[rec] - m_f);
    Lsum += scal[NREC + rec] * a;
    CNT  += scal[2 * NREC + rec];
    o  = fmaf(ws[rec * D + col], a, o);
    sm += ws[(size_t)NREC * D + rec * D + col];
    mx  = fmaxf(mx, ws[2 * (size_t)NREC * D + rec * D + col]);
    mn  = fminf(mn, ws[3 * (size_t)NREC * D + rec * D + col]);
  }
  float* ob = out + (size_t)b * 4 * D;
  ob[col]         = sm / (CNT + 1e-6f);
  ob[D + col]     = mx;
  ob[2 * D + col] = mn;
  ob[3 * D + col] = o / Lsum;
}

extern "C" void kernel_launch(void* const* d_in, const int* in_sizes, int n_in,
                              void* d_out, int out_size, void* d_ws, size_t ws_size,
                              hipStream_t stream) {
  const float* x    = (const float*)d_in[0];
  const int*   mask = (const int*)d_in[1];
  const float* w    = (const float*)d_in[2];
  float* out = (float*)d_out;
  float* ws  = (float*)d_ws;

  pool_stream<<<dim3(B * C), dim3(256), 0, stream>>>(x, mask, w, ws);
  pool_merge<<<dim3(B, 4), dim3(128), 0, stream>>>(ws, out);
}